// Round 10
// baseline (300.618 us; speedup 1.0000x reference)
//
#include <hip/hip_runtime.h>
#include <stdint.h>

#define THREADS 256
#define BPB 4                      // boards per block
#define CELLS (BPB * 81)           // 324 cells per block
#define PADW 12                    // padded floats/cell in prob buffer (b128-friendly)
#define NBLK (65536 / BPB)         // 16384 blocks
#define TOTAL_F4 (65536 * 81 * 9 / 4)   // 11943936 float4 in the logits tensor

__launch_bounds__(THREADS)
static __global__ void sudoku_main(const float* __restrict__ outs,
                                   const int*   __restrict__ targets,
                                   float*       __restrict__ partials) {
    __shared__ __align__(16) float P[CELLS * PADW];   // 15552 B probs only -> ~8 blocks/CU
    __shared__ float wave_sums[THREADS / 64];

    const int tid = threadIdx.x;
    const float4* __restrict__ f4 = (const float4*)outs;
    const int gbase = blockIdx.x * CELLS;             // first global cell of this block
    const int* __restrict__ tsrc = targets + gbase;

    // ---- Pass 1: cell-per-thread; 3 ALIGNED dwordx4 cover the 36B cell window ----
    // (no LDS staging, no vmcnt(0) drain: loads are plain VGPR loads the compiler
    //  can hoist/pipeline across both iterations; 18 lines/instr, 3x touch only)
    float acc_a = 0.0f;   // sum of (ce + 0.1*entropy) over owned cells
    #pragma unroll
    for (int it = 0; it < 2; ++it) {
        const int cell = tid + it * THREADS;
        if (cell < CELLS) {
            const int g  = gbase + cell;              // global cell index (< 5,308,416)
            const int d0 = 9 * g;                     // first dword of this cell
            int a = d0 >> 2;                          // aligned float4 window base
            a = (a > TOTAL_F4 - 3) ? (TOTAL_F4 - 3) : a;   // OOB guard (last cells)
            const int ofs = d0 - (a << 2);            // 0..3 within window
            const float4 w0 = f4[a], w1 = f4[a + 1], w2 = f4[a + 2];
            const float w[12] = { w0.x, w0.y, w0.z, w0.w,
                                  w1.x, w1.y, w1.z, w1.w,
                                  w2.x, w2.y, w2.z, w2.w };
            float x[9];
            #pragma unroll
            for (int j = 0; j < 9; ++j)               // static indices -> cndmask tree
                x[j] = (ofs == 0) ? w[j] : (ofs == 1) ? w[j + 1]
                     : (ofs == 2) ? w[j + 2] : w[j + 3];

            const int t = tsrc[cell];
            // no max-subtract: logits ~N(0,1); fp32 exp safe (r5-r9: absmax 0.0)
            float s = 0.0f, sx = 0.0f;
            float e[9];
            #pragma unroll
            for (int j = 0; j < 9; ++j) {
                e[j] = __expf(x[j]);
                s += e[j];
                sx = fmaf(e[j], x[j], sx);
            }
            float xt = x[0];
            #pragma unroll
            for (int j = 1; j < 9; ++j) xt = (j == t) ? x[j] : xt;
            const float lse = __logf(s);
            const float inv = __builtin_amdgcn_rcpf(s);
            acc_a += (lse - xt) + 0.1f * (lse - sx * inv);

            // probs -> padded LDS: b128 + b128 + b32 (r5-proven layout)
            float* __restrict__ pp = &P[cell * PADW];
            float4 p0, p1;
            p0.x = e[0] * inv; p0.y = e[1] * inv; p0.z = e[2] * inv; p0.w = e[3] * inv;
            p1.x = e[4] * inv; p1.y = e[5] * inv; p1.z = e[6] * inv; p1.w = e[7] * inv;
            *(float4*)pp       = p0;
            *(float4*)(pp + 4) = p1;
            pp[8] = e[8] * inv;
        }
    }
    __syncthreads();   // the ONLY barrier: probs visible for constraint sums

    // ---- Pass 2: one (board, unit) per thread; 27 units x 4 boards = 108 active ----
    float acc_c = 0.0f;
    if (tid < 27 * BPB) {
        const int q    = tid & 3;            // board within block
        const int u27  = tid >> 2;           // 0..26
        const int type = u27 / 9;            // 0=row 1=col 2=box
        const int unit = u27 - type * 9;
        const int ur3  = (unit / 3) * 3;
        const int uc3  = (unit % 3) * 3;
        const float* __restrict__ Pq = &P[q * 81 * PADW];

        float4 s03 = make_float4(0.f, 0.f, 0.f, 0.f);
        float4 s47 = make_float4(0.f, 0.f, 0.f, 0.f);
        float  s8  = 0.0f;
        #pragma unroll
        for (int j = 0; j < 9; ++j) {
            const int crow = unit * 9 + j;
            const int ccol = j * 9 + unit;
            const int cbox = (ur3 + j / 3) * 9 + uc3 + (j % 3);
            const int c = (type == 0) ? crow : ((type == 1) ? ccol : cbox);
            const float* __restrict__ cp = Pq + c * PADW;
            const float4 va = *(const float4*)cp;
            const float4 vb = *(const float4*)(cp + 4);
            s03.x += va.x; s03.y += va.y; s03.z += va.z; s03.w += va.w;
            s47.x += vb.x; s47.y += vb.y; s47.z += vb.z; s47.w += vb.w;
            s8    += cp[8];
        }
        float d0 = s03.x - 1.f, d1 = s03.y - 1.f, d2 = s03.z - 1.f, d3 = s03.w - 1.f;
        float d4 = s47.x - 1.f, d5 = s47.y - 1.f, d6 = s47.z - 1.f, d7 = s47.w - 1.f;
        float d8 = s8 - 1.f;
        acc_c = d0*d0 + d1*d1 + d2*d2 + d3*d3 + d4*d4 + d5*d5 + d6*d6 + d7*d7 + d8*d8;
    }

    // ---- Block reduce: pre-scaled partial -> plain store (no global atomics) ----
    // loss = sum(ce + 0.1*ent)/(B*81) + [0.5/(27*B*9)] * sum((s-1)^2)
    const float SA = 1.0f / (65536.0f * 81.0f);
    const float SB = 0.5f / (27.0f * 65536.0f * 9.0f);
    float total = acc_a * SA + acc_c * SB;
    #pragma unroll
    for (int off = 32; off > 0; off >>= 1)
        total += __shfl_down(total, off, 64);
    if ((tid & 63) == 0) wave_sums[tid >> 6] = total;
    __syncthreads();
    if (tid == 0)
        partials[blockIdx.x] = wave_sums[0] + wave_sums[1] + wave_sums[2] + wave_sums[3];
}

__launch_bounds__(256)
static __global__ void sudoku_final(const float* __restrict__ partials,
                                    float*       __restrict__ out) {
    __shared__ float wave_sums[4];
    const int tid = threadIdx.x;
    const float4* __restrict__ p4 = (const float4*)partials;
    float s = 0.0f;
    #pragma unroll 4
    for (int i = tid; i < NBLK / 4; i += 256) {   // coalesced float4
        const float4 v = p4[i];
        s += (v.x + v.y) + (v.z + v.w);
    }
    #pragma unroll
    for (int off = 32; off > 0; off >>= 1)
        s += __shfl_down(s, off, 64);
    if ((tid & 63) == 0) wave_sums[tid >> 6] = s;
    __syncthreads();
    if (tid == 0)
        out[0] = wave_sums[0] + wave_sums[1] + wave_sums[2] + wave_sums[3];
}

extern "C" void kernel_launch(void* const* d_in, const int* in_sizes, int n_in,
                              void* d_out, int out_size, void* d_ws, size_t ws_size,
                              hipStream_t stream) {
    const float* outs    = (const float*)d_in[0];
    const int*   targets = (const int*)d_in[1];
    float*       partials = (float*)d_ws;            // 16384 floats = 64 KB scratch
    hipLaunchKernelGGL(sudoku_main, dim3(NBLK), dim3(THREADS), 0, stream,
                       outs, targets, partials);
    hipLaunchKernelGGL(sudoku_final, dim3(1), dim3(256), 0, stream,
                       partials, (float*)d_out);
}